// Round 2
// baseline (76.108 us; speedup 1.0000x reference)
//
#include <hip/hip_runtime.h>

// MultiLabelAdaptiveMarginLoss: B=256, C=4096, K=32
// loss = (1/C) * sum_{b,k valid} sum_{j != t} relu(1 + (m_t - m_j) - (x_t - x_j))
// Rewrite: diff = a_k + c_j with a_k = 1 + m_t - x_t, c_j = x_j - m_j.
// j==t contributes relu(1)=1 -> sum over all j, subtract 1 per valid target
// (folded into acc init, only in the seg==0 block of each row).
//
// Decomposition probe: split each row across SEGS=4 blocks (1024 blocks x 256
// threads). Per-thread work: 1 float4 x 32 targets = 128 relu terms; fp-add
// chains of length 32 (4 independent chains). 4 blocks/CU, 16 waves/CU.
// If the measured 66 us contained hidden kernel time, this cuts it ~4x.
// If it's the harness poison-fill floor (~41 us 256 MiB fills in rocprof),
// dur will not move.

#define BB 256
#define CC 4096
#define KK 32
#define THREADS 256
#define SEGS 4                      // blocks per row; SEGS*THREADS*4 == CC

__global__ __launch_bounds__(THREADS) void mlam_fused(
    const float* __restrict__ input,
    const float* __restrict__ margin,
    const int* __restrict__ target,
    float* __restrict__ out) {

    __shared__ float sa[KK];               // a_k (=-1e30 for padded targets)
    __shared__ float swave[THREADS / 64];  // cross-wave partials

    const int blk = blockIdx.x;
    const int b   = blk >> 2;              // row
    const int seg = blk & (SEGS - 1);      // quarter of the row
    const int tid = threadIdx.x;
    const float* in_row = input  + (size_t)b * CC;
    const float* mg_row = margin + (size_t)b * CC;

    // Bulk loads first: 1 float4 of x and m per thread, coalesced.
    const int idx = seg * THREADS + tid;   // float4 index within row
    const float4 x = ((const float4*)in_row)[idx];
    const float4 m = ((const float4*)mg_row)[idx];

    // Lanes 0..31 gather per-target scalars. The j==t correction (-1 per
    // valid target) is applied once per row, by the seg==0 block only.
    float acc0 = 0.0f;
    if (tid < KK) {
        const int t = target[b * KK + tid];
        if (t >= 0) {
            sa[tid] = 1.0f + mg_row[t] - in_row[t];
            if (seg == 0) acc0 = -1.0f;
        } else {
            sa[tid] = -1e30f;   // relu(a+c) == 0 for all j
        }
    }
    __syncthreads();

    // Broadcast a_k into registers (same-address LDS reads broadcast free).
    float a[KK];
#pragma unroll
    for (int k = 0; k < KK; ++k) a[k] = sa[k];

    const float cx = x.x - m.x;
    const float cy = x.y - m.y;
    const float cz = x.z - m.z;
    const float cw = x.w - m.w;

    // 4 independent accumulator chains, 32 deps each.
    float ax = acc0, ay = 0.0f, az = 0.0f, aw = 0.0f;
#pragma unroll
    for (int k = 0; k < KK; ++k) {
        const float av = a[k];
        ax += fmaxf(av + cx, 0.0f);
        ay += fmaxf(av + cy, 0.0f);
        az += fmaxf(av + cz, 0.0f);
        aw += fmaxf(av + cw, 0.0f);
    }
    float acc = (ax + ay) + (az + aw);

    // Wave64 reduce, then cross-wave via LDS.
#pragma unroll
    for (int off = 32; off > 0; off >>= 1)
        acc += __shfl_down(acc, off, 64);
    if ((tid & 63) == 0) swave[tid >> 6] = acc;
    __syncthreads();

    if (tid == 0) {
        float tot = 0.0f;
#pragma unroll
        for (int w = 0; w < THREADS / 64; ++w) tot += swave[w];
        atomicAdd(out, tot * (1.0f / (float)CC));
    }
}

extern "C" void kernel_launch(void* const* d_in, const int* in_sizes, int n_in,
                              void* d_out, int out_size, void* d_ws, size_t ws_size,
                              hipStream_t stream) {
    const float* input  = (const float*)d_in[0];   // [B, C] fp32
    const float* margin = (const float*)d_in[1];   // [B, C] fp32
    const int*   target = (const int*)d_in[2];     // [B, K] int32
    float* out = (float*)d_out;                    // scalar

    hipMemsetAsync(out, 0, sizeof(float), stream);
    mlam_fused<<<BB * SEGS, THREADS, 0, stream>>>(input, margin, target, out);
}

// Round 3
// 67.461 us; speedup vs baseline: 1.1282x; 1.1282x over previous
//
#include <hip/hip_runtime.h>

// MultiLabelAdaptiveMarginLoss: B=256, C=4096, K=32
// loss = (1/C) * sum_{b,k valid} sum_{j != t} relu(1 + (m_t - m_j) - (x_t - x_j))
// Rewrite: diff = a_k + c_j with a_k = 1 + m_t - x_t, c_j = x_j - m_j.
// j==t contributes relu(1)=1 -> sum over all j, subtract 1 per valid target
// (folded into wave-0 lane-k accumulator init).
//
// Structure (best measured shape, r1 = 65.9 us): one block per row,
// 1024 threads. NO pre-compute __syncthreads: each wave redundantly gathers
// the K=32 per-target scalars with its own lanes 0..31 (L2-hits after the
// first wave) and broadcasts a_k across the wave via __shfl — so every
// wave's critical path is independent; no wave waits on another's scattered
// gather chain. c_j stays in registers (one float4 of x,m per thread).
// 4 independent fp-add chains of length 32. Single kernel + 4B memset;
// per-block result via one atomicAdd.

#define BB 256
#define CC 4096
#define KK 32
#define THREADS 1024          // CC/4 float4 elements, one per thread

__global__ __launch_bounds__(THREADS) void mlam_fused(
    const float* __restrict__ input,
    const float* __restrict__ margin,
    const int* __restrict__ target,
    float* __restrict__ out) {

    __shared__ float swave[THREADS / 64];  // cross-wave partials

    const int b    = blockIdx.x;
    const int tid  = threadIdx.x;
    const int lane = tid & 63;
    const float* in_row = input  + (size_t)b * CC;
    const float* mg_row = margin + (size_t)b * CC;

    // Bulk loads first; independent of the gather below, overlaps its latency.
    const float4 x = ((const float4*)in_row)[tid];
    const float4 m = ((const float4*)mg_row)[tid];

    // Per-wave gather: lanes 0..31 fetch target + per-target scalars.
    // Redundant across the 16 waves (all L2-hits after the first), but removes
    // the LDS staging and both __syncthreads from the critical path.
    float aval = -1e30f;       // padded target: relu(a+c) == 0 for all j
    float ax = 0.0f;           // chain 0 carries the j==t correction
    if (lane < KK) {
        const int t = target[b * KK + lane];
        if (t >= 0) {
            aval = 1.0f + mg_row[t] - in_row[t];
            if (tid < KK) ax = -1.0f;   // once per block (wave 0 only)
        }
    }

    // Broadcast a_k to all 64 lanes of this wave, in registers.
    float a[KK];
#pragma unroll
    for (int k = 0; k < KK; ++k) a[k] = __shfl(aval, k, 64);

    const float cx = x.x - m.x;
    const float cy = x.y - m.y;
    const float cz = x.z - m.z;
    const float cw = x.w - m.w;

    // 4 independent accumulator chains, 32 deps each.
    float ay = 0.0f, az = 0.0f, aw = 0.0f;
#pragma unroll
    for (int k = 0; k < KK; ++k) {
        const float av = a[k];
        ax += fmaxf(av + cx, 0.0f);
        ay += fmaxf(av + cy, 0.0f);
        az += fmaxf(av + cz, 0.0f);
        aw += fmaxf(av + cw, 0.0f);
    }
    float acc = (ax + ay) + (az + aw);

    // Wave64 reduce, then cross-wave via LDS (the only block barrier).
#pragma unroll
    for (int off = 32; off > 0; off >>= 1)
        acc += __shfl_down(acc, off, 64);
    if (lane == 0) swave[tid >> 6] = acc;
    __syncthreads();

    if (tid == 0) {
        float tot = 0.0f;
#pragma unroll
        for (int w = 0; w < THREADS / 64; ++w) tot += swave[w];
        atomicAdd(out, tot * (1.0f / (float)CC));
    }
}

extern "C" void kernel_launch(void* const* d_in, const int* in_sizes, int n_in,
                              void* d_out, int out_size, void* d_ws, size_t ws_size,
                              hipStream_t stream) {
    const float* input  = (const float*)d_in[0];   // [B, C] fp32
    const float* margin = (const float*)d_in[1];   // [B, C] fp32
    const int*   target = (const int*)d_in[2];     // [B, K] int32
    float* out = (float*)d_out;                    // scalar

    hipMemsetAsync(out, 0, sizeof(float), stream);
    mlam_fused<<<BB, THREADS, 0, stream>>>(input, margin, target, out);
}

// Round 4
// 66.825 us; speedup vs baseline: 1.1389x; 1.0095x over previous
//
#include <hip/hip_runtime.h>

// MultiLabelAdaptiveMarginLoss: B=256, C=4096, K=32
// loss = (1/C) * sum_{b,k valid} sum_{j != t} relu(1 + (m_t - m_j) - (x_t - x_j))
// Rewrite: diff = a_k + c_j with a_k = 1 + m_t - x_t, c_j = x_j - m_j.
// j==t contributes relu(1)=1 -> sum over all j, subtract 1 per valid target
// (folded into the lane-k accumulator init).
//
// Best-measured structure (r1 = 65.9 us): one block per row, 1024 threads,
// c_j in registers (one float4 of x,m per thread), a_k staged in LDS by
// lanes 0..31 with a single barrier, 4 independent fp-add chains of length
// 32. Single kernel + 4B memset; per-block result via one atomicAdd.
// This round's only change vs r1: the target load is issued FIRST — it heads
// the longest dependency chain (target -> scattered gather -> sa -> barrier
// that all 16 waves wait on), so it should not queue behind 8 KB of bulk
// load requests.

#define BB 256
#define CC 4096
#define KK 32
#define THREADS 1024          // CC/4 float4 elements, one per thread

__global__ __launch_bounds__(THREADS) void mlam_fused(
    const float* __restrict__ input,
    const float* __restrict__ margin,
    const int* __restrict__ target,
    float* __restrict__ out) {

    __shared__ float sa[KK];               // a_k (=-1e30 for padded targets)
    __shared__ float swave[THREADS / 64];  // cross-wave partials

    const int b   = blockIdx.x;
    const int tid = threadIdx.x;
    const float* in_row = input  + (size_t)b * CC;
    const float* mg_row = margin + (size_t)b * CC;

    // Head of the longest chain: issue the target load before anything else.
    int t = -1;
    if (tid < KK) t = target[b * KK + tid];

    // Bulk loads: 1 float4 of x and m per thread, coalesced.
    const float4 x = ((const float4*)in_row)[tid];
    const float4 m = ((const float4*)mg_row)[tid];

    // Lanes 0..31 gather per-target scalars. A valid target contributes
    // relu(1)=1 at j==t which must be removed: init that lane's acc to -1.
    float acc0 = 0.0f;
    if (tid < KK) {
        if (t >= 0) {
            sa[tid] = 1.0f + mg_row[t] - in_row[t];
            acc0 = -1.0f;
        } else {
            sa[tid] = -1e30f;   // relu(a+c) == 0 for all j
        }
    }
    __syncthreads();

    // Broadcast a_k into registers (same-address LDS reads broadcast free).
    float a[KK];
#pragma unroll
    for (int k = 0; k < KK; ++k) a[k] = sa[k];

    const float cx = x.x - m.x;
    const float cy = x.y - m.y;
    const float cz = x.z - m.z;
    const float cw = x.w - m.w;

    // 4 independent accumulator chains, 32 deps each.
    float ax = acc0, ay = 0.0f, az = 0.0f, aw = 0.0f;
#pragma unroll
    for (int k = 0; k < KK; ++k) {
        const float av = a[k];
        ax += fmaxf(av + cx, 0.0f);
        ay += fmaxf(av + cy, 0.0f);
        az += fmaxf(av + cz, 0.0f);
        aw += fmaxf(av + cw, 0.0f);
    }
    float acc = (ax + ay) + (az + aw);

    // Wave64 reduce, then cross-wave via LDS.
#pragma unroll
    for (int off = 32; off > 0; off >>= 1)
        acc += __shfl_down(acc, off, 64);
    if ((tid & 63) == 0) swave[tid >> 6] = acc;
    __syncthreads();

    if (tid == 0) {
        float tot = 0.0f;
#pragma unroll
        for (int w = 0; w < THREADS / 64; ++w) tot += swave[w];
        atomicAdd(out, tot * (1.0f / (float)CC));
    }
}

extern "C" void kernel_launch(void* const* d_in, const int* in_sizes, int n_in,
                              void* d_out, int out_size, void* d_ws, size_t ws_size,
                              hipStream_t stream) {
    const float* input  = (const float*)d_in[0];   // [B, C] fp32
    const float* margin = (const float*)d_in[1];   // [B, C] fp32
    const int*   target = (const int*)d_in[2];     // [B, K] int32
    float* out = (float*)d_out;                    // scalar

    hipMemsetAsync(out, 0, sizeof(float), stream);
    mlam_fused<<<BB, THREADS, 0, stream>>>(input, margin, target, out);
}